// Round 15
// baseline (7086.574 us; speedup 1.0000x reference)
//
#include <hip/hip_runtime.h>

#define DEV static __device__ __forceinline__

typedef _Float16 half8  __attribute__((ext_vector_type(8)));
typedef _Float16 half4v __attribute__((ext_vector_type(4)));
typedef float    floatx4 __attribute__((ext_vector_type(4)));
typedef unsigned int u32;
typedef unsigned long long u64;
typedef u32 u32x4 __attribute__((ext_vector_type(4)));

// Split scale: lo = f16((v - f16(v)) * 1024); combine = hi + lo/1024.
#define SPLIT_S 1024.0f
#define SPLIT_R (1.0f / 1024.0f)

// async global->LDS, 16B/lane: LDS dest wave-uniform base + lane*16.
DEV void gl_lds16(const _Float16* g, _Float16* l) {
  __builtin_amdgcn_global_load_lds(
      (const __attribute__((address_space(1))) u32*)g,
      (__attribute__((address_space(3))) u32*)l, 16, 0, 0);
}

// LLC-coherent (bypass L1/L2) 16B load. Freshness via sc0+sc1.
DEV u32x4 llc_load16(u64 addr) {
  u32x4 r;
  asm volatile("global_load_dwordx4 %0, %1, off sc0 sc1"
               : "=v"(r) : "v"(addr));
  return r;
}
// No-return atomic swaps: execute & complete AT the MALL -> cheap vmcnt ack.
DEV void mall_swap8(u64 addr, u64 v) {
  asm volatile("global_atomic_swap_x2 %0, %1, off"
               :: "v"(addr), "v"(v) : "memory");
}
DEV void mall_swap4(u64 addr, int v) {
  asm volatile("global_atomic_swap %0, %1, off"
               :: "v"(addr), "v"(v) : "memory");
}

// Overflow-safe fast tanh: tanh(x) = sign(x) * (1 - 2/(1+e^{2|x|})).
DEV float fast_tanh(float x) {
  const float e = __expf(2.0f * fabsf(x));
  return copysignf(1.0f - 2.0f / (1.0f + e), x);
}

// ---------------------------------------------------------------------------
// ws layout (bytes), peak 84.02 MB:
//   0         : Uhi (33,554,432)  -> OUTS aliases later
//   33554432  : Ulo (33,554,432)  -> WoutF aliases later
//   67108864  : Whi region (8,388,608)  Win-hi then Wx-hi
//   75497472  : Wlo region (8,388,608)  Win-lo then Wx-lo
//   83886080  : hpub (131,072) chunk-transposed
//   84017152  : flags (512)
// d_out: x-splits (67.1MB) until GEMM1 done, then wx fp32 [t][b][d], then y.
// ---------------------------------------------------------------------------
__global__ __launch_bounds__(256) void k_split_xw(
    const float* __restrict__ x, const float* __restrict__ win,
    _Float16* __restrict__ xhi, _Float16* __restrict__ xlo,
    _Float16* __restrict__ whi, _Float16* __restrict__ wlo)
{
  const int NX4 = (8192 * 2048) / 4;
  const int NW4 = (2048 * 2048) / 4;
  for (int i = blockIdx.x * 256 + threadIdx.x; i < NX4 + NW4; i += gridDim.x * 256) {
    const float* src; _Float16* dh; _Float16* dl; int j = i;
    if (j < NX4) { src = x; dh = xhi; dl = xlo; }
    else         { j -= NX4; src = win; dh = whi; dl = wlo; }
    const float4 v = ((const float4*)src)[j];
    half4v h, l;
#pragma unroll
    for (int q = 0; q < 4; ++q) {
      const float a = ((const float*)&v)[q];
      const _Float16 hh = (_Float16)a;
      h[q] = hh;
      l[q] = (_Float16)((a - (float)hh) * SPLIT_S);
    }
    ((half4v*)dh)[j] = h;
    ((half4v*)dl)[j] = l;
  }
}

// Split Wx into W-region (Win splits dead); init hpub parity0; zero flags.
// h_pub CHUNK-TRANSPOSED layout (bytes):
//   [parity(2) stride 65536][part(2) stride 32768][kchunk(256) stride 128][row(8) stride 16]
__global__ __launch_bounds__(256) void k_convertB(
    const float* __restrict__ wx, const float* __restrict__ h0,
    _Float16* __restrict__ Wxhi, _Float16* __restrict__ Wxlo,
    char* __restrict__ hpub, int* __restrict__ flags)
{
  if (blockIdx.x == 0 && threadIdx.x < 128) flags[threadIdx.x] = 0;
  const int NW4 = (2048 * 2048) / 4;
  for (int i = blockIdx.x * 256 + threadIdx.x; i < NW4; i += gridDim.x * 256) {
    const float4 v = ((const float4*)wx)[i];
    half4v h, l;
#pragma unroll
    for (int j = 0; j < 4; ++j) {
      const float a = ((const float*)&v)[j];
      const _Float16 hh = (_Float16)a;
      h[j] = hh;
      l[j] = (_Float16)((a - (float)hh) * SPLIT_S);
    }
    ((half4v*)Wxhi)[i] = h;
    ((half4v*)Wxlo)[i] = l;
  }
  for (int id = blockIdx.x * 256 + threadIdx.x; id < 2048; id += gridDim.x * 256) {
    const int c = id >> 3, b = id & 7;
    union { _Float16 h[8]; u32x4 v; } hi, lo;
#pragma unroll
    for (int j = 0; j < 8; ++j) {
      const float v = h0[b * 2048 + c * 8 + j];
      const _Float16 h = (_Float16)v;
      hi.h[j] = h;
      lo.h[j] = (_Float16)((v - (float)h) * SPLIT_S);
    }
    *(u32x4*)(hpub + c * 128 + b * 16)         = hi.v;
    *(u32x4*)(hpub + 32768 + c * 128 + b * 16) = lo.v;
  }
}

// Convert Wout -> f16 (into dead Ulo region).
__global__ __launch_bounds__(256) void k_convert2(
    const float* __restrict__ wout, _Float16* __restrict__ WoutF)
{
  const int NW4 = (2048 * 2048) / 4;
  for (int i = blockIdx.x * 256 + threadIdx.x; i < NW4; i += gridDim.x * 256) {
    const float4 v = ((const float4*)wout)[i];
    half4v o;
    o[0] = (_Float16)v.x; o[1] = (_Float16)v.y;
    o[2] = (_Float16)v.z; o[3] = (_Float16)v.w;
    ((half4v*)WoutF)[i] = o;
  }
}

// ---------------------------------------------------------------------------
// Split-f16 GEMM with PRE-SPLIT f16 operands (pure async staging).
// EPI 0: silu -> pre-split hi/lo f16.  EPI 1: + bias -> fp32 wx layout.
template <int EPI>
__global__ __launch_bounds__(256) void k_gemm_ps(
    const _Float16* __restrict__ Ahi, const _Float16* __restrict__ Alo,
    const _Float16* __restrict__ Bhi, const _Float16* __restrict__ Blo,
    _Float16* __restrict__ Chi, _Float16* __restrict__ Clo,
    float* __restrict__ Cf, const float* __restrict__ bias,
    int M, int N, int K)
{
  __shared__ _Float16 Ah[4096], Al[4096], Bh[4096], Bl[4096];
  const int tid  = threadIdx.x;
  const int lane = tid & 63, wave = tid >> 6;
  const int wm = wave >> 1, wn = wave & 1;
  const int tm = blockIdx.y * 128, tn = blockIdx.x * 128;
  const int lr = lane & 15, lk = lane >> 4;
  const int r0 = tid >> 2;
  const int c0 = (tid & 3) * 8;

  floatx4 acch[4][4] = {};
  floatx4 accl[4][4] = {};

  for (int k0 = 0; k0 < K; k0 += 32) {
#pragma unroll
    for (int c = 0; c < 2; ++c) {
      const int row = c * 64 + r0;
      const size_t aoff = (size_t)(tm + row) * K + k0 + c0;
      const size_t boff = (size_t)(tn + row) * K + k0 + c0;
      gl_lds16(Ahi + aoff, Ah + c * 2048 + wave * 512);
      gl_lds16(Alo + aoff, Al + c * 2048 + wave * 512);
      gl_lds16(Bhi + boff, Bh + c * 2048 + wave * 512);
      gl_lds16(Blo + boff, Bl + c * 2048 + wave * 512);
    }
    __syncthreads();

    half8 fah[4], fal[4], fbh[4], fbl[4];
#pragma unroll
    for (int mi = 0; mi < 4; ++mi) {
      const int off = (wm * 64 + mi * 16 + lr) * 32 + lk * 8;
      fah[mi] = *(const half8*)(Ah + off);
      fal[mi] = *(const half8*)(Al + off);
    }
#pragma unroll
    for (int ni = 0; ni < 4; ++ni) {
      const int off = (wn * 64 + ni * 16 + lr) * 32 + lk * 8;
      fbh[ni] = *(const half8*)(Bh + off);
      fbl[ni] = *(const half8*)(Bl + off);
    }
#pragma unroll
    for (int mi = 0; mi < 4; ++mi)
#pragma unroll
      for (int ni = 0; ni < 4; ++ni) {
        acch[mi][ni] = __builtin_amdgcn_mfma_f32_16x16x32_f16(fah[mi], fbh[ni], acch[mi][ni], 0, 0, 0);
        accl[mi][ni] = __builtin_amdgcn_mfma_f32_16x16x32_f16(
            fah[mi], fbl[ni],
            __builtin_amdgcn_mfma_f32_16x16x32_f16(fal[mi], fbh[ni], accl[mi][ni], 0, 0, 0),
            0, 0, 0);
      }
    __syncthreads();
  }

#pragma unroll
  for (int mi = 0; mi < 4; ++mi)
#pragma unroll
    for (int ni = 0; ni < 4; ++ni) {
      const int gcol = tn + wn * 64 + ni * 16 + lr;
#pragma unroll
      for (int r = 0; r < 4; ++r) {
        const int grow = tm + wm * 64 + mi * 16 + lk * 4 + r;
        const float v = acch[mi][ni][r] + accl[mi][ni][r] * SPLIT_R;
        if (EPI == 0) {
          const float s = v / (1.0f + __expf(-v));
          const _Float16 sh = (_Float16)s;
          Chi[(size_t)grow * N + gcol] = sh;
          Clo[(size_t)grow * N + gcol] = (_Float16)((s - (float)sh) * SPLIT_S);
        } else {
          const int tt = grow & 1023, bb = grow >> 10;
          Cf[(size_t)(tt * 8 + bb) * N + gcol] = v + bias[gcol];
        }
      }
    }
}

// ---------------------------------------------------------------------------
// Plain-f16 GEMM for y = (outs/8) . Wout^T, epilogue *8.
__global__ __launch_bounds__(256) void k_gemm_out(
    const _Float16* __restrict__ A, const _Float16* __restrict__ B,
    float* __restrict__ C, int M, int N, int K)
{
  __shared__ _Float16 As[4096];
  __shared__ _Float16 Bs[4096];
  const int tid  = threadIdx.x;
  const int lane = tid & 63, wave = tid >> 6;
  const int wm = wave >> 1, wn = wave & 1;
  const int tm = blockIdx.y * 128, tn = blockIdx.x * 128;
  const int lr = lane & 15, lk = lane >> 4;
  const int r0 = tid >> 2;
  const int c0 = (tid & 3) * 8;

  floatx4 acc[4][4] = {};

  for (int k0 = 0; k0 < K; k0 += 32) {
#pragma unroll
    for (int c = 0; c < 2; ++c) {
      const int row = c * 64 + r0;
      gl_lds16(A + (size_t)(tm + row) * K + k0 + c0, As + c * 2048 + wave * 512);
      gl_lds16(B + (size_t)(tn + row) * K + k0 + c0, Bs + c * 2048 + wave * 512);
    }
    __syncthreads();

    half8 af[4], bf[4];
#pragma unroll
    for (int mi = 0; mi < 4; ++mi)
      af[mi] = *(const half8*)(As + (wm * 64 + mi * 16 + lr) * 32 + lk * 8);
#pragma unroll
    for (int ni = 0; ni < 4; ++ni)
      bf[ni] = *(const half8*)(Bs + (wn * 64 + ni * 16 + lr) * 32 + lk * 8);
#pragma unroll
    for (int mi = 0; mi < 4; ++mi)
#pragma unroll
      for (int ni = 0; ni < 4; ++ni)
        acc[mi][ni] = __builtin_amdgcn_mfma_f32_16x16x32_f16(af[mi], bf[ni], acc[mi][ni], 0, 0, 0);
    __syncthreads();
  }

#pragma unroll
  for (int mi = 0; mi < 4; ++mi)
#pragma unroll
    for (int ni = 0; ni < 4; ++ni) {
      const int gcol = tn + wn * 64 + ni * 16 + lr;
#pragma unroll
      for (int r = 0; r < 4; ++r) {
        const int grow = tm + wm * 64 + mi * 16 + lk * 4 + r;
        C[(size_t)grow * N + gcol] = acc[mi][ni][r] * 8.0f;
      }
    }
}

// ---------------------------------------------------------------------------
// Persistent recurrence — r14 base with two recur-local changes:
//  (1) PARALLEL 4-WAVE TAIL: wave w owns cols e0+4w..+4 (8 batches x 4 cols);
//      each wave does its own reduce/tanh/split/swaps/ack in parallel;
//      barrier D then a single flag. Serial tail VALU / 4.
//  (2) DUAL-STREAM STAGGERED POLL: two in-flight flag samples offset ~256cy
//      -> sampling period ~RT/2; full vmcnt(0) drain on break keeps the
//      gather's counted vmcnt(16) exact (vmcnt retires oldest-first).
__global__ __launch_bounds__(256, 1) void k_recur(
    const float* __restrict__ Wh, const float* __restrict__ wxp,
    const float* __restrict__ h0p, const float* __restrict__ lalpha,
    _Float16* __restrict__ outs, char* __restrict__ h_pub, int* flags)
{
  __shared__ float red[256 * 4];   // 4KB (cross-wave reduce only)
  const int tid = threadIdx.x;
  const int lane = tid & 63, wave = tid >> 6;
  const int g = blockIdx.x;
  const int e0 = g * 16;
  const int lr = lane & 15, lk = lane >> 4;
  const int lrc = lr & 7;   // gather: lanes lr>=8 duplicate row lr-8 (dead B cols)
  const float alpha = __expf(lalpha[0]);

  // Preload + split W_h fragments (fp32 global -> hi/lo f16 regs), once.
  half8 afh[16], afl[16];
#pragma unroll
  for (int ks = 0; ks < 16; ++ks) {
    const float* wp = Wh + (size_t)(e0 + lr) * 2048 + wave * 512 + ks * 32 + lk * 8;
    const float4 f0 = *(const float4*)wp;
    const float4 f1 = *(const float4*)(wp + 4);
    half8 h, l;
#pragma unroll
    for (int j = 0; j < 4; ++j) {
      const float a0 = ((const float*)&f0)[j], a1 = ((const float*)&f1)[j];
      const _Float16 h0_ = (_Float16)a0;
      const _Float16 h1_ = (_Float16)a1;
      h[j]     = h0_; l[j]     = (_Float16)((a0 - (float)h0_) * SPLIT_S);
      h[j + 4] = h1_; l[j + 4] = (_Float16)((a1 - (float)h1_) * SPLIT_S);
    }
    afh[ks] = h; afl[ks] = l;
  }

  // Tail ownership: EVERY wave, lanes 0..7: (batch = lane, cols e0+4*wave..+4).
  const bool owner = (lane < 8);
  float hr0 = 0.f, hr1 = 0.f, hr2 = 0.f, hr3 = 0.f;
  if (owner) {
    const float4 hv = *(const float4*)(h0p + (size_t)lane * 2048 + e0 + wave * 4);
    hr0 = hv.x; hr1 = hv.y; hr2 = hv.z; hr3 = hv.w;
  }

  const u64 hbase = (u64)h_pub;
  const u64 flag_base = (u64)flags;
  // Per-lane gather base: chunk (wave*64 + ks*4 + lk), row lrc.
  const u64 gb_off = (u64)((wave * 64 + lk) * 128 + lrc * 16);

  for (int t = 0; t < 1024; ++t) {
    // Prefetch wx_t (plain cached; consumed in tail).
    float4 wv = {0.f, 0.f, 0.f, 0.f};
    if (owner) wv = *(const float4*)(wxp + (size_t)(t * 8 + lane) * 2048 + e0 + wave * 4);

    // Dual-stream staggered poll (wave 0 only): lane watches flags[2l],[2l+1].
    if (t > 0 && wave == 0) {
      const u64 fp = flag_base + (u64)lane * 8;
      u64 f1, f2;
      asm volatile("global_load_dwordx2 %0, %1, off sc0 sc1" : "=v"(f1) : "v"(fp));
      __builtin_amdgcn_s_sleep(4);   // ~256cy stagger between streams
      asm volatile("global_load_dwordx2 %0, %1, off sc0 sc1" : "=v"(f2) : "v"(fp));
      for (;;) {
        asm volatile("s_waitcnt vmcnt(1)" ::: "memory");   // f1 (oldest) done
        __builtin_amdgcn_sched_barrier(0);
        if (__all(((int)f1 >= t) && ((int)(f1 >> 32) >= t))) break;
        asm volatile("global_load_dwordx2 %0, %1, off sc0 sc1" : "=v"(f1) : "v"(fp));
        asm volatile("s_waitcnt vmcnt(1)" ::: "memory");   // f2 done
        __builtin_amdgcn_sched_barrier(0);
        if (__all(((int)f2 >= t) && ((int)(f2 >> 32) >= t))) break;
        asm volatile("global_load_dwordx2 %0, %1, off sc0 sc1" : "=v"(f2) : "v"(fp));
      }
      asm volatile("s_waitcnt vmcnt(0)" ::: "memory");     // drain stray sample
      __builtin_amdgcn_sched_barrier(0);
    }
    __syncthreads();   // A

    // ---- register-direct gather: hi then lo, all 32 loads in flight ----
    const u64 pb = hbase + (u64)(t & 1) * 65536 + gb_off;
    u32x4 sh[16], sl[16];
#pragma unroll
    for (int ks = 0; ks < 16; ++ks) sh[ks] = llc_load16(pb + (u64)ks * 512);
#pragma unroll
    for (int ks = 0; ks < 16; ++ks) sl[ks] = llc_load16(pb + 32768 + (u64)ks * 512);
    asm volatile("s_waitcnt vmcnt(16)" ::: "memory");   // wv + 16 hi done (oldest-first)
    __builtin_amdgcn_sched_barrier(0);

    // ---- hi MFMAs: ph += Ah.Bh ; pl += Al.Bh (lo loads still in flight) ----
    floatx4 ph[4] = {};
    floatx4 pl[4] = {};
#pragma unroll
    for (int ks = 0; ks < 16; ++ks) {
      const half8 bh = __builtin_bit_cast(half8, sh[ks]);
      ph[ks & 3] = __builtin_amdgcn_mfma_f32_16x16x32_f16(afh[ks], bh, ph[ks & 3], 0, 0, 0);
      pl[ks & 3] = __builtin_amdgcn_mfma_f32_16x16x32_f16(afl[ks], bh, pl[ks & 3], 0, 0, 0);
    }
    asm volatile("s_waitcnt vmcnt(0)" ::: "memory");    // lo complete
    __builtin_amdgcn_sched_barrier(0);

    // ---- lo MFMAs: pl += Ah.Bl ----
#pragma unroll
    for (int ks = 0; ks < 16; ++ks) {
      const half8 bl = __builtin_bit_cast(half8, sl[ks]);
      pl[ks & 3] = __builtin_amdgcn_mfma_f32_16x16x32_f16(afh[ks], bl, pl[ks & 3], 0, 0, 0);
    }
    const floatx4 pt = (ph[0] + ph[1] + ph[2] + ph[3]) +
                       (pl[0] + pl[1] + pl[2] + pl[3]) * SPLIT_R;
    *(floatx4*)&red[(wave * 64 + lane) * 4] = pt;
    __syncthreads();   // C

    // ---- PARALLEL TAIL: each wave handles its 8x4 block ----
    union { _Float16 h[4]; u64 u; } hv, lv, ov;
    if (owner) {
      const floatx4* R = (const floatx4*)red;
      const int fi = wave * 16 + lane;   // frag index: col-group=wave, row=lane
      const floatx4 s = R[fi] + R[64 + fi] + R[128 + fi] + R[192 + fi];
      hr0 += alpha * fast_tanh(s[0] + wv.x);
      hr1 += alpha * fast_tanh(s[1] + wv.y);
      hr2 += alpha * fast_tanh(s[2] + wv.z);
      hr3 += alpha * fast_tanh(s[3] + wv.w);
      hv.h[0] = (_Float16)hr0; hv.h[1] = (_Float16)hr1;
      hv.h[2] = (_Float16)hr2; hv.h[3] = (_Float16)hr3;
      lv.h[0] = (_Float16)((hr0 - (float)hv.h[0]) * SPLIT_S);
      lv.h[1] = (_Float16)((hr1 - (float)hv.h[1]) * SPLIT_S);
      lv.h[2] = (_Float16)((hr2 - (float)hv.h[2]) * SPLIT_S);
      lv.h[3] = (_Float16)((hr3 - (float)hv.h[3]) * SPLIT_S);
      // MALL-atomic publish: chunk 2g+(wave>>1), row lane, byte-half (wave&1).
      const u64 dst = hbase + (u64)((t + 1) & 1) * 65536 +
                      (u64)((2 * g + (wave >> 1)) * 128 + lane * 16 + (wave & 1) * 8);
      mall_swap8(dst,         hv.u);   // hi
      mall_swap8(dst + 32768, lv.u);   // lo
      // Compute outs payload while the swaps fly.
      ov.h[0] = (_Float16)((hr0 * hr0 / (1.f + __expf(-hr0))) * 0.125f);
      ov.h[1] = (_Float16)((hr1 * hr1 / (1.f + __expf(-hr1))) * 0.125f);
      ov.h[2] = (_Float16)((hr2 * hr2 / (1.f + __expf(-hr2))) * 0.125f);
      ov.h[3] = (_Float16)((hr3 * hr3 / (1.f + __expf(-hr3))) * 0.125f);
    }
    asm volatile("s_waitcnt vmcnt(0)" ::: "memory");   // this wave's swaps acked
    __syncthreads();   // D — all four waves' h(t+1) globally visible
    if (tid == 0) mall_swap4(flag_base + (u64)g * 4, t + 1);
    if (owner)
      *(u64*)(outs + (size_t)(lane * 1024 + t) * 2048 + e0 + wave * 4) = ov.u;
    // red(t+1) overwrite safe: all waves pass barrier A (after wave0's poll)
    // before writing red, and every wave's red(t) reads completed before D.
  }
}

// ---------------------------------------------------------------------------
extern "C" void kernel_launch(void* const* d_in, const int* in_sizes, int n_in,
                              void* d_out, int out_size, void* d_ws, size_t ws_size,
                              hipStream_t stream)
{
  (void)in_sizes; (void)n_in; (void)out_size; (void)ws_size;
  const float* x    = (const float*)d_in[0];
  const float* h0   = (const float*)d_in[1];
  const float* Win  = (const float*)d_in[2];
  const float* Wx   = (const float*)d_in[3];
  const float* Wh   = (const float*)d_in[4];
  const float* bias = (const float*)d_in[5];
  const float* lal  = (const float*)d_in[6];
  const float* Wout = (const float*)d_in[7];

  char* ws = (char*)d_ws;
  _Float16* Uhi   = (_Float16*)(ws);                 // 33,554,432 B
  _Float16* Ulo   = (_Float16*)(ws + 33554432);      // 33,554,432 B
  _Float16* OUTS  = (_Float16*)(ws);                 // aliases Uhi
  _Float16* WoutF = (_Float16*)(ws + 33554432);      // aliases Ulo
  _Float16* Whi   = (_Float16*)(ws + 67108864);      //  8,388,608 B
  _Float16* Wlo   = (_Float16*)(ws + 75497472);      //  8,388,608 B
  char*     hpub  = ws + 83886080;                   //    131,072 B
  int*      flags = (int*)(ws + 84017152);           //        512 B
  _Float16* xhi   = (_Float16*)d_out;                // 33,554,432 B
  _Float16* xlo   = (_Float16*)((char*)d_out + 33554432);
  float*    wxbuf = (float*)d_out;

  const dim3 gg(16, 64);  // N/128, M/128

  k_split_xw<<<2048, 256, 0, stream>>>(x, Win, xhi, xlo, Whi, Wlo);
  k_gemm_ps<0><<<gg, 256, 0, stream>>>(xhi, xlo, Whi, Wlo, Uhi, Ulo,
                                       nullptr, nullptr, 8192, 2048, 2048);
  k_convertB<<<512, 256, 0, stream>>>(Wx, h0, Whi, Wlo, hpub, flags);
  k_gemm_ps<1><<<gg, 256, 0, stream>>>(Uhi, Ulo, Whi, Wlo, nullptr, nullptr,
                                       wxbuf, bias, 8192, 2048, 2048);
  k_convert2<<<512, 256, 0, stream>>>(Wout, WoutF);
  k_recur<<<128, 256, 0, stream>>>(Wh, wxbuf, h0, lal, OUTS, hpub, flags);
  k_gemm_out<<<gg, 256, 0, stream>>>(OUTS, WoutF, (float*)d_out, 8192, 2048, 2048);
}

// Round 16
// 4215.924 us; speedup vs baseline: 1.6809x; 1.6809x over previous
//
#include <hip/hip_runtime.h>

#define DEV static __device__ __forceinline__

typedef _Float16 half8  __attribute__((ext_vector_type(8)));
typedef _Float16 half4v __attribute__((ext_vector_type(4)));
typedef float    floatx4 __attribute__((ext_vector_type(4)));
typedef unsigned int u32;
typedef unsigned long long u64;
typedef u32 u32x4 __attribute__((ext_vector_type(4)));

// Split scale: lo = f16((v - f16(v)) * 1024); combine = hi + lo/1024.
#define SPLIT_S 1024.0f
#define SPLIT_R (1.0f / 1024.0f)

// async global->LDS, 16B/lane: LDS dest wave-uniform base + lane*16.
DEV void gl_lds16(const _Float16* g, _Float16* l) {
  __builtin_amdgcn_global_load_lds(
      (const __attribute__((address_space(1))) u32*)g,
      (__attribute__((address_space(3))) u32*)l, 16, 0, 0);
}

// LLC-coherent (bypass L1/L2) 16B load. Freshness via sc0+sc1.
DEV u32x4 llc_load16(u64 addr) {
  u32x4 r;
  asm volatile("global_load_dwordx4 %0, %1, off sc0 sc1"
               : "=v"(r) : "v"(addr));
  return r;
}
// No-return atomic swaps: execute & complete AT the MALL -> cheap vmcnt ack.
DEV void mall_swap8(u64 addr, u64 v) {
  asm volatile("global_atomic_swap_x2 %0, %1, off"
               :: "v"(addr), "v"(v) : "memory");
}
DEV void mall_swap4(u64 addr, int v) {
  asm volatile("global_atomic_swap %0, %1, off"
               :: "v"(addr), "v"(v) : "memory");
}

// Overflow-safe fast tanh: tanh(x) = sign(x) * (1 - 2/(1+e^{2|x|})).
DEV float fast_tanh(float x) {
  const float e = __expf(2.0f * fabsf(x));
  return copysignf(1.0f - 2.0f / (1.0f + e), x);
}

// ---------------------------------------------------------------------------
// ws layout (bytes), peak 84.02 MB:
//   0         : Uhi (33,554,432)  -> OUTS aliases later
//   33554432  : Ulo (33,554,432)  -> WoutF aliases later
//   67108864  : Whi region (8,388,608)  Win-hi then Wx-hi
//   75497472  : Wlo region (8,388,608)  Win-lo then Wx-lo
//   83886080  : hpub (131,072) chunk-transposed
//   84017152  : flags (512)
// d_out: x-splits (67.1MB) until GEMM1 done, then wx fp32 [t][b][d], then y.
// ---------------------------------------------------------------------------
__global__ __launch_bounds__(256) void k_split_xw(
    const float* __restrict__ x, const float* __restrict__ win,
    _Float16* __restrict__ xhi, _Float16* __restrict__ xlo,
    _Float16* __restrict__ whi, _Float16* __restrict__ wlo)
{
  const int NX4 = (8192 * 2048) / 4;
  const int NW4 = (2048 * 2048) / 4;
  for (int i = blockIdx.x * 256 + threadIdx.x; i < NX4 + NW4; i += gridDim.x * 256) {
    const float* src; _Float16* dh; _Float16* dl; int j = i;
    if (j < NX4) { src = x; dh = xhi; dl = xlo; }
    else         { j -= NX4; src = win; dh = whi; dl = wlo; }
    const float4 v = ((const float4*)src)[j];
    half4v h, l;
#pragma unroll
    for (int q = 0; q < 4; ++q) {
      const float a = ((const float*)&v)[q];
      const _Float16 hh = (_Float16)a;
      h[q] = hh;
      l[q] = (_Float16)((a - (float)hh) * SPLIT_S);
    }
    ((half4v*)dh)[j] = h;
    ((half4v*)dl)[j] = l;
  }
}

// Split Wx into W-region (Win splits dead); init hpub parity0; zero flags.
// h_pub CHUNK-TRANSPOSED layout (bytes):
//   [parity(2) stride 65536][part(2) stride 32768][kchunk(256) stride 128][row(8) stride 16]
__global__ __launch_bounds__(256) void k_convertB(
    const float* __restrict__ wx, const float* __restrict__ h0,
    _Float16* __restrict__ Wxhi, _Float16* __restrict__ Wxlo,
    char* __restrict__ hpub, int* __restrict__ flags)
{
  if (blockIdx.x == 0 && threadIdx.x < 128) flags[threadIdx.x] = 0;
  const int NW4 = (2048 * 2048) / 4;
  for (int i = blockIdx.x * 256 + threadIdx.x; i < NW4; i += gridDim.x * 256) {
    const float4 v = ((const float4*)wx)[i];
    half4v h, l;
#pragma unroll
    for (int j = 0; j < 4; ++j) {
      const float a = ((const float*)&v)[j];
      const _Float16 hh = (_Float16)a;
      h[j] = hh;
      l[j] = (_Float16)((a - (float)hh) * SPLIT_S);
    }
    ((half4v*)Wxhi)[i] = h;
    ((half4v*)Wxlo)[i] = l;
  }
  for (int id = blockIdx.x * 256 + threadIdx.x; id < 2048; id += gridDim.x * 256) {
    const int c = id >> 3, b = id & 7;
    union { _Float16 h[8]; u32x4 v; } hi, lo;
#pragma unroll
    for (int j = 0; j < 8; ++j) {
      const float v = h0[b * 2048 + c * 8 + j];
      const _Float16 h = (_Float16)v;
      hi.h[j] = h;
      lo.h[j] = (_Float16)((v - (float)h) * SPLIT_S);
    }
    *(u32x4*)(hpub + c * 128 + b * 16)         = hi.v;
    *(u32x4*)(hpub + 32768 + c * 128 + b * 16) = lo.v;
  }
}

// Convert Wout -> f16 (into dead Ulo region).
__global__ __launch_bounds__(256) void k_convert2(
    const float* __restrict__ wout, _Float16* __restrict__ WoutF)
{
  const int NW4 = (2048 * 2048) / 4;
  for (int i = blockIdx.x * 256 + threadIdx.x; i < NW4; i += gridDim.x * 256) {
    const float4 v = ((const float4*)wout)[i];
    half4v o;
    o[0] = (_Float16)v.x; o[1] = (_Float16)v.y;
    o[2] = (_Float16)v.z; o[3] = (_Float16)v.w;
    ((half4v*)WoutF)[i] = o;
  }
}

// ---------------------------------------------------------------------------
// Split-f16 GEMM with PRE-SPLIT f16 operands (pure async staging).
// EPI 0: silu -> pre-split hi/lo f16.  EPI 1: + bias -> fp32 wx layout.
template <int EPI>
__global__ __launch_bounds__(256) void k_gemm_ps(
    const _Float16* __restrict__ Ahi, const _Float16* __restrict__ Alo,
    const _Float16* __restrict__ Bhi, const _Float16* __restrict__ Blo,
    _Float16* __restrict__ Chi, _Float16* __restrict__ Clo,
    float* __restrict__ Cf, const float* __restrict__ bias,
    int M, int N, int K)
{
  __shared__ _Float16 Ah[4096], Al[4096], Bh[4096], Bl[4096];
  const int tid  = threadIdx.x;
  const int lane = tid & 63, wave = tid >> 6;
  const int wm = wave >> 1, wn = wave & 1;
  const int tm = blockIdx.y * 128, tn = blockIdx.x * 128;
  const int lr = lane & 15, lk = lane >> 4;
  const int r0 = tid >> 2;
  const int c0 = (tid & 3) * 8;

  floatx4 acch[4][4] = {};
  floatx4 accl[4][4] = {};

  for (int k0 = 0; k0 < K; k0 += 32) {
#pragma unroll
    for (int c = 0; c < 2; ++c) {
      const int row = c * 64 + r0;
      const size_t aoff = (size_t)(tm + row) * K + k0 + c0;
      const size_t boff = (size_t)(tn + row) * K + k0 + c0;
      gl_lds16(Ahi + aoff, Ah + c * 2048 + wave * 512);
      gl_lds16(Alo + aoff, Al + c * 2048 + wave * 512);
      gl_lds16(Bhi + boff, Bh + c * 2048 + wave * 512);
      gl_lds16(Blo + boff, Bl + c * 2048 + wave * 512);
    }
    __syncthreads();

    half8 fah[4], fal[4], fbh[4], fbl[4];
#pragma unroll
    for (int mi = 0; mi < 4; ++mi) {
      const int off = (wm * 64 + mi * 16 + lr) * 32 + lk * 8;
      fah[mi] = *(const half8*)(Ah + off);
      fal[mi] = *(const half8*)(Al + off);
    }
#pragma unroll
    for (int ni = 0; ni < 4; ++ni) {
      const int off = (wn * 64 + ni * 16 + lr) * 32 + lk * 8;
      fbh[ni] = *(const half8*)(Bh + off);
      fbl[ni] = *(const half8*)(Bl + off);
    }
#pragma unroll
    for (int mi = 0; mi < 4; ++mi)
#pragma unroll
      for (int ni = 0; ni < 4; ++ni) {
        acch[mi][ni] = __builtin_amdgcn_mfma_f32_16x16x32_f16(fah[mi], fbh[ni], acch[mi][ni], 0, 0, 0);
        accl[mi][ni] = __builtin_amdgcn_mfma_f32_16x16x32_f16(
            fah[mi], fbl[ni],
            __builtin_amdgcn_mfma_f32_16x16x32_f16(fal[mi], fbh[ni], accl[mi][ni], 0, 0, 0),
            0, 0, 0);
      }
    __syncthreads();
  }

#pragma unroll
  for (int mi = 0; mi < 4; ++mi)
#pragma unroll
    for (int ni = 0; ni < 4; ++ni) {
      const int gcol = tn + wn * 64 + ni * 16 + lr;
#pragma unroll
      for (int r = 0; r < 4; ++r) {
        const int grow = tm + wm * 64 + mi * 16 + lk * 4 + r;
        const float v = acch[mi][ni][r] + accl[mi][ni][r] * SPLIT_R;
        if (EPI == 0) {
          const float s = v / (1.0f + __expf(-v));
          const _Float16 sh = (_Float16)s;
          Chi[(size_t)grow * N + gcol] = sh;
          Clo[(size_t)grow * N + gcol] = (_Float16)((s - (float)sh) * SPLIT_S);
        } else {
          const int tt = grow & 1023, bb = grow >> 10;
          Cf[(size_t)(tt * 8 + bb) * N + gcol] = v + bias[gcol];
        }
      }
    }
}

// ---------------------------------------------------------------------------
// Plain-f16 GEMM for y = (outs/8) . Wout^T, epilogue *8.
__global__ __launch_bounds__(256) void k_gemm_out(
    const _Float16* __restrict__ A, const _Float16* __restrict__ B,
    float* __restrict__ C, int M, int N, int K)
{
  __shared__ _Float16 As[4096];
  __shared__ _Float16 Bs[4096];
  const int tid  = threadIdx.x;
  const int lane = tid & 63, wave = tid >> 6;
  const int wm = wave >> 1, wn = wave & 1;
  const int tm = blockIdx.y * 128, tn = blockIdx.x * 128;
  const int lr = lane & 15, lk = lane >> 4;
  const int r0 = tid >> 2;
  const int c0 = (tid & 3) * 8;

  floatx4 acc[4][4] = {};

  for (int k0 = 0; k0 < K; k0 += 32) {
#pragma unroll
    for (int c = 0; c < 2; ++c) {
      const int row = c * 64 + r0;
      gl_lds16(A + (size_t)(tm + row) * K + k0 + c0, As + c * 2048 + wave * 512);
      gl_lds16(B + (size_t)(tn + row) * K + k0 + c0, Bs + c * 2048 + wave * 512);
    }
    __syncthreads();

    half8 af[4], bf[4];
#pragma unroll
    for (int mi = 0; mi < 4; ++mi)
      af[mi] = *(const half8*)(As + (wm * 64 + mi * 16 + lr) * 32 + lk * 8);
#pragma unroll
    for (int ni = 0; ni < 4; ++ni)
      bf[ni] = *(const half8*)(Bs + (wn * 64 + ni * 16 + lr) * 32 + lk * 8);
#pragma unroll
    for (int mi = 0; mi < 4; ++mi)
#pragma unroll
      for (int ni = 0; ni < 4; ++ni)
        acc[mi][ni] = __builtin_amdgcn_mfma_f32_16x16x32_f16(af[mi], bf[ni], acc[mi][ni], 0, 0, 0);
    __syncthreads();
  }

#pragma unroll
  for (int mi = 0; mi < 4; ++mi)
#pragma unroll
    for (int ni = 0; ni < 4; ++ni) {
      const int gcol = tn + wn * 64 + ni * 16 + lr;
#pragma unroll
      for (int r = 0; r < 4; ++r) {
        const int grow = tm + wm * 64 + mi * 16 + lk * 4 + r;
        C[(size_t)grow * N + gcol] = acc[mi][ni][r] * 8.0f;
      }
    }
}

// ---------------------------------------------------------------------------
// Persistent recurrence — r14 structure verbatim (empirical best: wave0 tail,
// full-coverage MALL-atomic publish, single-stream poll) with ONE micro-
// reorder: outs payload (ov) computed BETWEEN the h-swaps and the vmcnt(0)
// ack, hiding ~100cy of VALU under the MALL ack. Flag right after ack.
__global__ __launch_bounds__(256, 1) void k_recur(
    const float* __restrict__ Wh, const float* __restrict__ wxp,
    const float* __restrict__ h0p, const float* __restrict__ lalpha,
    _Float16* __restrict__ outs, char* __restrict__ h_pub, int* flags)
{
  __shared__ float red[256 * 4];   // 4KB (cross-wave reduce only)
  const int tid = threadIdx.x;
  const int lane = tid & 63, wave = tid >> 6;
  const int g = blockIdx.x;
  const int e0 = g * 16;
  const int lr = lane & 15, lk = lane >> 4;
  const int lrc = lr & 7;   // lanes lr>=8 duplicate row lr-8 (dead B cols)
  const float alpha = __expf(lalpha[0]);

  // Preload + split W_h fragments (fp32 global -> hi/lo f16 regs), once.
  half8 afh[16], afl[16];
#pragma unroll
  for (int ks = 0; ks < 16; ++ks) {
    const float* wp = Wh + (size_t)(e0 + lr) * 2048 + wave * 512 + ks * 32 + lk * 8;
    const float4 f0 = *(const float4*)wp;
    const float4 f1 = *(const float4*)(wp + 4);
    half8 h, l;
#pragma unroll
    for (int j = 0; j < 4; ++j) {
      const float a0 = ((const float*)&f0)[j], a1 = ((const float*)&f1)[j];
      const _Float16 h0_ = (_Float16)a0;
      const _Float16 h1_ = (_Float16)a1;
      h[j]     = h0_; l[j]     = (_Float16)((a0 - (float)h0_) * SPLIT_S);
      h[j + 4] = h1_; l[j + 4] = (_Float16)((a1 - (float)h1_) * SPLIT_S);
    }
    afh[ks] = h; afl[ks] = l;
  }

  const bool owner = (tid < 64) && (lr < 8);  // owns (batch lr, cols e0+lk*4..+4)
  float hr0 = 0.f, hr1 = 0.f, hr2 = 0.f, hr3 = 0.f;
  if (owner) {
    const float4 hv = *(const float4*)(h0p + (size_t)lr * 2048 + e0 + lk * 4);
    hr0 = hv.x; hr1 = hv.y; hr2 = hv.z; hr3 = hv.w;
  }

  const u64 hbase = (u64)h_pub;
  const u64 flag_base = (u64)flags;
  // Per-lane gather base: chunk (wave*64 + ks*4 + lk), row lrc.
  const u64 gb_off = (u64)((wave * 64 + lk) * 128 + lrc * 16);

  for (int t = 0; t < 1024; ++t) {
    // Prefetch wx_t (plain cached; consumed in tail, hidden under poll+gather).
    float4 wv = {0.f, 0.f, 0.f, 0.f};
    if (owner) wv = *(const float4*)(wxp + (size_t)(t * 8 + lr) * 2048 + e0 + lk * 4);

    // Poll: wave 0 only; lane watches flags[2*lane], flags[2*lane+1].
    if (t > 0 && wave == 0) {
      const u64* fp = (const u64*)flags + lane;
      for (;;) {
        const u64 fv = __hip_atomic_load(fp, __ATOMIC_RELAXED, __HIP_MEMORY_SCOPE_AGENT);
        if (__all(((int)fv >= t) && ((int)(fv >> 32) >= t))) break;
        __builtin_amdgcn_s_sleep(1);
      }
    }
    __syncthreads();   // A

    // ---- register-direct gather: hi then lo, all 32 loads in flight ----
    const u64 pb = hbase + (u64)(t & 1) * 65536 + gb_off;
    u32x4 sh[16], sl[16];
#pragma unroll
    for (int ks = 0; ks < 16; ++ks) sh[ks] = llc_load16(pb + (u64)ks * 512);
#pragma unroll
    for (int ks = 0; ks < 16; ++ks) sl[ks] = llc_load16(pb + 32768 + (u64)ks * 512);
    asm volatile("s_waitcnt vmcnt(16)" ::: "memory");   // hi complete
    __builtin_amdgcn_sched_barrier(0);

    // ---- hi MFMAs: ph += Ah.Bh ; pl += Al.Bh (lo loads still in flight) ----
    floatx4 ph[4] = {};
    floatx4 pl[4] = {};
#pragma unroll
    for (int ks = 0; ks < 16; ++ks) {
      const half8 bh = __builtin_bit_cast(half8, sh[ks]);
      ph[ks & 3] = __builtin_amdgcn_mfma_f32_16x16x32_f16(afh[ks], bh, ph[ks & 3], 0, 0, 0);
      pl[ks & 3] = __builtin_amdgcn_mfma_f32_16x16x32_f16(afl[ks], bh, pl[ks & 3], 0, 0, 0);
    }
    asm volatile("s_waitcnt vmcnt(0)" ::: "memory");    // lo complete
    __builtin_amdgcn_sched_barrier(0);

    // ---- lo MFMAs: pl += Ah.Bl ----
#pragma unroll
    for (int ks = 0; ks < 16; ++ks) {
      const half8 bl = __builtin_bit_cast(half8, sl[ks]);
      pl[ks & 3] = __builtin_amdgcn_mfma_f32_16x16x32_f16(afh[ks], bl, pl[ks & 3], 0, 0, 0);
    }
    const floatx4 pt = (ph[0] + ph[1] + ph[2] + ph[3]) +
                       (pl[0] + pl[1] + pl[2] + pl[3]) * SPLIT_R;
    *(floatx4*)&red[(wave * 64 + lane) * 4] = pt;
    __syncthreads();   // C

    if (tid < 64) {
      const floatx4* R = (const floatx4*)red;
      const floatx4 s = R[lane] + R[64 + lane] + R[128 + lane] + R[192 + lane];
      union { _Float16 h[4]; u64 u; } hv, lv, ov;
      if (owner) {
        hr0 += alpha * fast_tanh(s[0] + wv.x);
        hr1 += alpha * fast_tanh(s[1] + wv.y);
        hr2 += alpha * fast_tanh(s[2] + wv.z);
        hr3 += alpha * fast_tanh(s[3] + wv.w);
        hv.h[0] = (_Float16)hr0; hv.h[1] = (_Float16)hr1;
        hv.h[2] = (_Float16)hr2; hv.h[3] = (_Float16)hr3;
        lv.h[0] = (_Float16)((hr0 - (float)hv.h[0]) * SPLIT_S);
        lv.h[1] = (_Float16)((hr1 - (float)hv.h[1]) * SPLIT_S);
        lv.h[2] = (_Float16)((hr2 - (float)hv.h[2]) * SPLIT_S);
        lv.h[3] = (_Float16)((hr3 - (float)hv.h[3]) * SPLIT_S);
        // MALL-atomic publish: chunk 2g+(lk>>1), row lr, byte-half (lk&1).
        // 32 owner lanes -> full-coverage 256B contiguous per instruction.
        const u64 dst = hbase + (u64)((t + 1) & 1) * 65536 +
                        (u64)((2 * g + (lk >> 1)) * 128 + lr * 16 + (lk & 1) * 8);
        mall_swap8(dst,         hv.u);   // hi
        mall_swap8(dst + 32768, lv.u);   // lo
        // Compute outs payload NOW -> hides part of the swap-ack latency.
        ov.h[0] = (_Float16)((hr0 * hr0 / (1.f + __expf(-hr0))) * 0.125f);
        ov.h[1] = (_Float16)((hr1 * hr1 / (1.f + __expf(-hr1))) * 0.125f);
        ov.h[2] = (_Float16)((hr2 * hr2 / (1.f + __expf(-hr2))) * 0.125f);
        ov.h[3] = (_Float16)((hr3 * hr3 / (1.f + __expf(-hr3))) * 0.125f);
      }
      // Ack at MALL (atomics complete at the coherence point), then flag.
      asm volatile("s_waitcnt vmcnt(0)" ::: "memory");
      if (lane == 0) mall_swap4(flag_base + (u64)g * 4, t + 1);
      if (owner) {
        // outs consumed only by the next dispatch -> off the critical path.
        *(u64*)(outs + (size_t)(lr * 1024 + t) * 2048 + e0 + lk * 4) = ov.u;
      }
    }
    // red overwrite for t+1 is safe: waves block at barrier A until wave0
    // (which finished its red reads) arrives there after the tail.
  }
}

// ---------------------------------------------------------------------------
extern "C" void kernel_launch(void* const* d_in, const int* in_sizes, int n_in,
                              void* d_out, int out_size, void* d_ws, size_t ws_size,
                              hipStream_t stream)
{
  (void)in_sizes; (void)n_in; (void)out_size; (void)ws_size;
  const float* x    = (const float*)d_in[0];
  const float* h0   = (const float*)d_in[1];
  const float* Win  = (const float*)d_in[2];
  const float* Wx   = (const float*)d_in[3];
  const float* Wh   = (const float*)d_in[4];
  const float* bias = (const float*)d_in[5];
  const float* lal  = (const float*)d_in[6];
  const float* Wout = (const float*)d_in[7];

  char* ws = (char*)d_ws;
  _Float16* Uhi   = (_Float16*)(ws);                 // 33,554,432 B
  _Float16* Ulo   = (_Float16*)(ws + 33554432);      // 33,554,432 B
  _Float16* OUTS  = (_Float16*)(ws);                 // aliases Uhi
  _Float16* WoutF = (_Float16*)(ws + 33554432);      // aliases Ulo
  _Float16* Whi   = (_Float16*)(ws + 67108864);      //  8,388,608 B
  _Float16* Wlo   = (_Float16*)(ws + 75497472);      //  8,388,608 B
  char*     hpub  = ws + 83886080;                   //    131,072 B
  int*      flags = (int*)(ws + 84017152);           //        512 B
  _Float16* xhi   = (_Float16*)d_out;                // 33,554,432 B
  _Float16* xlo   = (_Float16*)((char*)d_out + 33554432);
  float*    wxbuf = (float*)d_out;

  const dim3 gg(16, 64);  // N/128, M/128

  k_split_xw<<<2048, 256, 0, stream>>>(x, Win, xhi, xlo, Whi, Wlo);
  k_gemm_ps<0><<<gg, 256, 0, stream>>>(xhi, xlo, Whi, Wlo, Uhi, Ulo,
                                       nullptr, nullptr, 8192, 2048, 2048);
  k_convertB<<<512, 256, 0, stream>>>(Wx, h0, Whi, Wlo, hpub, flags);
  k_gemm_ps<1><<<gg, 256, 0, stream>>>(Uhi, Ulo, Whi, Wlo, nullptr, nullptr,
                                       wxbuf, bias, 8192, 2048, 2048);
  k_convert2<<<512, 256, 0, stream>>>(Wout, WoutF);
  k_recur<<<128, 256, 0, stream>>>(Wh, wxbuf, h0, lal, OUTS, hpub, flags);
  k_gemm_out<<<gg, 256, 0, stream>>>(OUTS, WoutF, (float*)d_out, 8192, 2048, 2048);
}

// Round 17
// 4180.210 us; speedup vs baseline: 1.6953x; 1.0085x over previous
//
#include <hip/hip_runtime.h>

#define DEV static __device__ __forceinline__

typedef _Float16 half8  __attribute__((ext_vector_type(8)));
typedef _Float16 half4v __attribute__((ext_vector_type(4)));
typedef float    floatx4 __attribute__((ext_vector_type(4)));
typedef unsigned int u32;
typedef unsigned long long u64;
typedef u32 u32x4 __attribute__((ext_vector_type(4)));

// Split scale: lo = f16((v - f16(v)) * 1024); combine = hi + lo/1024.
#define SPLIT_S 1024.0f
#define SPLIT_R (1.0f / 1024.0f)

// async global->LDS, 16B/lane: LDS dest wave-uniform base + lane*16.
DEV void gl_lds16(const _Float16* g, _Float16* l) {
  __builtin_amdgcn_global_load_lds(
      (const __attribute__((address_space(1))) u32*)g,
      (__attribute__((address_space(3))) u32*)l, 16, 0, 0);
}

// LLC-coherent (bypass L1/L2) 16B load. Freshness via sc0+sc1.
DEV u32x4 llc_load16(u64 addr) {
  u32x4 r;
  asm volatile("global_load_dwordx4 %0, %1, off sc0 sc1"
               : "=v"(r) : "v"(addr));
  return r;
}
// No-return atomic swaps: execute & complete AT the MALL -> cheap vmcnt ack.
DEV void mall_swap8(u64 addr, u64 v) {
  asm volatile("global_atomic_swap_x2 %0, %1, off"
               :: "v"(addr), "v"(v) : "memory");
}
DEV void mall_swap4(u64 addr, int v) {
  asm volatile("global_atomic_swap %0, %1, off"
               :: "v"(addr), "v"(v) : "memory");
}

// Overflow-safe fast tanh: tanh(x) = sign(x) * (1 - 2/(1+e^{2|x|})).
DEV float fast_tanh(float x) {
  const float e = __expf(2.0f * fabsf(x));
  return copysignf(1.0f - 2.0f / (1.0f + e), x);
}

// ---------------------------------------------------------------------------
// ws layout (bytes), peak 84.02 MB:
//   0         : Uhi (33,554,432)  -> OUTS aliases later
//   33554432  : Ulo (33,554,432)  -> WoutF aliases later
//   67108864  : Whi region (8,388,608)  Win-hi then Wx-hi
//   75497472  : Wlo region (8,388,608)  Win-lo then Wx-lo
//   83886080  : hpub (131,072) chunk-transposed
//   84017152  : flags (512)
// d_out: x-splits (67.1MB) until GEMM1 done, then wx fp32 [t][b][d], then y.
// ---------------------------------------------------------------------------
__global__ __launch_bounds__(256) void k_split_xw(
    const float* __restrict__ x, const float* __restrict__ win,
    _Float16* __restrict__ xhi, _Float16* __restrict__ xlo,
    _Float16* __restrict__ whi, _Float16* __restrict__ wlo)
{
  const int NX4 = (8192 * 2048) / 4;
  const int NW4 = (2048 * 2048) / 4;
  for (int i = blockIdx.x * 256 + threadIdx.x; i < NX4 + NW4; i += gridDim.x * 256) {
    const float* src; _Float16* dh; _Float16* dl; int j = i;
    if (j < NX4) { src = x; dh = xhi; dl = xlo; }
    else         { j -= NX4; src = win; dh = whi; dl = wlo; }
    const float4 v = ((const float4*)src)[j];
    half4v h, l;
#pragma unroll
    for (int q = 0; q < 4; ++q) {
      const float a = ((const float*)&v)[q];
      const _Float16 hh = (_Float16)a;
      h[q] = hh;
      l[q] = (_Float16)((a - (float)hh) * SPLIT_S);
    }
    ((half4v*)dh)[j] = h;
    ((half4v*)dl)[j] = l;
  }
}

// Split Wx into W-region (Win splits dead); init hpub parity0; zero flags.
// h_pub CHUNK-TRANSPOSED layout (bytes):
//   [parity(2) stride 65536][part(2) stride 32768][kchunk(256) stride 128][row(8) stride 16]
__global__ __launch_bounds__(256) void k_convertB(
    const float* __restrict__ wx, const float* __restrict__ h0,
    _Float16* __restrict__ Wxhi, _Float16* __restrict__ Wxlo,
    char* __restrict__ hpub, int* __restrict__ flags)
{
  if (blockIdx.x == 0 && threadIdx.x < 128) flags[threadIdx.x] = 0;
  const int NW4 = (2048 * 2048) / 4;
  for (int i = blockIdx.x * 256 + threadIdx.x; i < NW4; i += gridDim.x * 256) {
    const float4 v = ((const float4*)wx)[i];
    half4v h, l;
#pragma unroll
    for (int j = 0; j < 4; ++j) {
      const float a = ((const float*)&v)[j];
      const _Float16 hh = (_Float16)a;
      h[j] = hh;
      l[j] = (_Float16)((a - (float)hh) * SPLIT_S);
    }
    ((half4v*)Wxhi)[i] = h;
    ((half4v*)Wxlo)[i] = l;
  }
  for (int id = blockIdx.x * 256 + threadIdx.x; id < 2048; id += gridDim.x * 256) {
    const int c = id >> 3, b = id & 7;
    union { _Float16 h[8]; u32x4 v; } hi, lo;
#pragma unroll
    for (int j = 0; j < 8; ++j) {
      const float v = h0[b * 2048 + c * 8 + j];
      const _Float16 h = (_Float16)v;
      hi.h[j] = h;
      lo.h[j] = (_Float16)((v - (float)h) * SPLIT_S);
    }
    *(u32x4*)(hpub + c * 128 + b * 16)         = hi.v;
    *(u32x4*)(hpub + 32768 + c * 128 + b * 16) = lo.v;
  }
}

// Convert Wout -> f16 (into dead Ulo region).
__global__ __launch_bounds__(256) void k_convert2(
    const float* __restrict__ wout, _Float16* __restrict__ WoutF)
{
  const int NW4 = (2048 * 2048) / 4;
  for (int i = blockIdx.x * 256 + threadIdx.x; i < NW4; i += gridDim.x * 256) {
    const float4 v = ((const float4*)wout)[i];
    half4v o;
    o[0] = (_Float16)v.x; o[1] = (_Float16)v.y;
    o[2] = (_Float16)v.z; o[3] = (_Float16)v.w;
    ((half4v*)WoutF)[i] = o;
  }
}

// ---------------------------------------------------------------------------
// Split-f16 GEMM with PRE-SPLIT f16 operands (pure async staging).
// EPI 0: silu -> pre-split hi/lo f16.  EPI 1: + bias -> fp32 wx layout.
template <int EPI>
__global__ __launch_bounds__(256) void k_gemm_ps(
    const _Float16* __restrict__ Ahi, const _Float16* __restrict__ Alo,
    const _Float16* __restrict__ Bhi, const _Float16* __restrict__ Blo,
    _Float16* __restrict__ Chi, _Float16* __restrict__ Clo,
    float* __restrict__ Cf, const float* __restrict__ bias,
    int M, int N, int K)
{
  __shared__ _Float16 Ah[4096], Al[4096], Bh[4096], Bl[4096];
  const int tid  = threadIdx.x;
  const int lane = tid & 63, wave = tid >> 6;
  const int wm = wave >> 1, wn = wave & 1;
  const int tm = blockIdx.y * 128, tn = blockIdx.x * 128;
  const int lr = lane & 15, lk = lane >> 4;
  const int r0 = tid >> 2;
  const int c0 = (tid & 3) * 8;

  floatx4 acch[4][4] = {};
  floatx4 accl[4][4] = {};

  for (int k0 = 0; k0 < K; k0 += 32) {
#pragma unroll
    for (int c = 0; c < 2; ++c) {
      const int row = c * 64 + r0;
      const size_t aoff = (size_t)(tm + row) * K + k0 + c0;
      const size_t boff = (size_t)(tn + row) * K + k0 + c0;
      gl_lds16(Ahi + aoff, Ah + c * 2048 + wave * 512);
      gl_lds16(Alo + aoff, Al + c * 2048 + wave * 512);
      gl_lds16(Bhi + boff, Bh + c * 2048 + wave * 512);
      gl_lds16(Blo + boff, Bl + c * 2048 + wave * 512);
    }
    __syncthreads();

    half8 fah[4], fal[4], fbh[4], fbl[4];
#pragma unroll
    for (int mi = 0; mi < 4; ++mi) {
      const int off = (wm * 64 + mi * 16 + lr) * 32 + lk * 8;
      fah[mi] = *(const half8*)(Ah + off);
      fal[mi] = *(const half8*)(Al + off);
    }
#pragma unroll
    for (int ni = 0; ni < 4; ++ni) {
      const int off = (wn * 64 + ni * 16 + lr) * 32 + lk * 8;
      fbh[ni] = *(const half8*)(Bh + off);
      fbl[ni] = *(const half8*)(Bl + off);
    }
#pragma unroll
    for (int mi = 0; mi < 4; ++mi)
#pragma unroll
      for (int ni = 0; ni < 4; ++ni) {
        acch[mi][ni] = __builtin_amdgcn_mfma_f32_16x16x32_f16(fah[mi], fbh[ni], acch[mi][ni], 0, 0, 0);
        accl[mi][ni] = __builtin_amdgcn_mfma_f32_16x16x32_f16(
            fah[mi], fbl[ni],
            __builtin_amdgcn_mfma_f32_16x16x32_f16(fal[mi], fbh[ni], accl[mi][ni], 0, 0, 0),
            0, 0, 0);
      }
    __syncthreads();
  }

#pragma unroll
  for (int mi = 0; mi < 4; ++mi)
#pragma unroll
    for (int ni = 0; ni < 4; ++ni) {
      const int gcol = tn + wn * 64 + ni * 16 + lr;
#pragma unroll
      for (int r = 0; r < 4; ++r) {
        const int grow = tm + wm * 64 + mi * 16 + lk * 4 + r;
        const float v = acch[mi][ni][r] + accl[mi][ni][r] * SPLIT_R;
        if (EPI == 0) {
          const float s = v / (1.0f + __expf(-v));
          const _Float16 sh = (_Float16)s;
          Chi[(size_t)grow * N + gcol] = sh;
          Clo[(size_t)grow * N + gcol] = (_Float16)((s - (float)sh) * SPLIT_S);
        } else {
          const int tt = grow & 1023, bb = grow >> 10;
          Cf[(size_t)(tt * 8 + bb) * N + gcol] = v + bias[gcol];
        }
      }
    }
}

// ---------------------------------------------------------------------------
// Plain-f16 GEMM for y = (outs/8) . Wout^T, epilogue *8.
__global__ __launch_bounds__(256) void k_gemm_out(
    const _Float16* __restrict__ A, const _Float16* __restrict__ B,
    float* __restrict__ C, int M, int N, int K)
{
  __shared__ _Float16 As[4096];
  __shared__ _Float16 Bs[4096];
  const int tid  = threadIdx.x;
  const int lane = tid & 63, wave = tid >> 6;
  const int wm = wave >> 1, wn = wave & 1;
  const int tm = blockIdx.y * 128, tn = blockIdx.x * 128;
  const int lr = lane & 15, lk = lane >> 4;
  const int r0 = tid >> 2;
  const int c0 = (tid & 3) * 8;

  floatx4 acc[4][4] = {};

  for (int k0 = 0; k0 < K; k0 += 32) {
#pragma unroll
    for (int c = 0; c < 2; ++c) {
      const int row = c * 64 + r0;
      gl_lds16(A + (size_t)(tm + row) * K + k0 + c0, As + c * 2048 + wave * 512);
      gl_lds16(B + (size_t)(tn + row) * K + k0 + c0, Bs + c * 2048 + wave * 512);
    }
    __syncthreads();

    half8 af[4], bf[4];
#pragma unroll
    for (int mi = 0; mi < 4; ++mi)
      af[mi] = *(const half8*)(As + (wm * 64 + mi * 16 + lr) * 32 + lk * 8);
#pragma unroll
    for (int ni = 0; ni < 4; ++ni)
      bf[ni] = *(const half8*)(Bs + (wn * 64 + ni * 16 + lr) * 32 + lk * 8);
#pragma unroll
    for (int mi = 0; mi < 4; ++mi)
#pragma unroll
      for (int ni = 0; ni < 4; ++ni)
        acc[mi][ni] = __builtin_amdgcn_mfma_f32_16x16x32_f16(af[mi], bf[ni], acc[mi][ni], 0, 0, 0);
    __syncthreads();
  }

#pragma unroll
  for (int mi = 0; mi < 4; ++mi)
#pragma unroll
    for (int ni = 0; ni < 4; ++ni) {
      const int gcol = tn + wn * 64 + ni * 16 + lr;
#pragma unroll
      for (int r = 0; r < 4; ++r) {
        const int grow = tm + wm * 64 + mi * 16 + lk * 4 + r;
        C[(size_t)grow * N + gcol] = acc[mi][ni][r] * 8.0f;
      }
    }
}

// ---------------------------------------------------------------------------
// Persistent recurrence — r7 structure with MALL-atomic publish (r14, best
// measured: 3315 us). Flag protocol + register-direct chunk-transposed
// gather. 128 WGs x 256 thr (1 WG/CU).
__global__ __launch_bounds__(256, 1) void k_recur(
    const float* __restrict__ Wh, const float* __restrict__ wxp,
    const float* __restrict__ h0p, const float* __restrict__ lalpha,
    _Float16* __restrict__ outs, char* __restrict__ h_pub, int* flags)
{
  __shared__ float red[256 * 4];   // 4KB (cross-wave reduce only)
  const int tid = threadIdx.x;
  const int lane = tid & 63, wave = tid >> 6;
  const int g = blockIdx.x;
  const int e0 = g * 16;
  const int lr = lane & 15, lk = lane >> 4;
  const int lrc = lr & 7;   // lanes lr>=8 duplicate row lr-8 (dead B cols)
  const float alpha = __expf(lalpha[0]);

  // Preload + split W_h fragments (fp32 global -> hi/lo f16 regs), once.
  half8 afh[16], afl[16];
#pragma unroll
  for (int ks = 0; ks < 16; ++ks) {
    const float* wp = Wh + (size_t)(e0 + lr) * 2048 + wave * 512 + ks * 32 + lk * 8;
    const float4 f0 = *(const float4*)wp;
    const float4 f1 = *(const float4*)(wp + 4);
    half8 h, l;
#pragma unroll
    for (int j = 0; j < 4; ++j) {
      const float a0 = ((const float*)&f0)[j], a1 = ((const float*)&f1)[j];
      const _Float16 h0_ = (_Float16)a0;
      const _Float16 h1_ = (_Float16)a1;
      h[j]     = h0_; l[j]     = (_Float16)((a0 - (float)h0_) * SPLIT_S);
      h[j + 4] = h1_; l[j + 4] = (_Float16)((a1 - (float)h1_) * SPLIT_S);
    }
    afh[ks] = h; afl[ks] = l;
  }

  const bool owner = (tid < 64) && (lr < 8);  // owns (batch lr, cols e0+lk*4..+4)
  float hr0 = 0.f, hr1 = 0.f, hr2 = 0.f, hr3 = 0.f;
  if (owner) {
    const float4 hv = *(const float4*)(h0p + (size_t)lr * 2048 + e0 + lk * 4);
    hr0 = hv.x; hr1 = hv.y; hr2 = hv.z; hr3 = hv.w;
  }

  const u64 hbase = (u64)h_pub;
  const u64 flag_base = (u64)flags;
  // Per-lane gather base: chunk (wave*64 + ks*4 + lk), row lrc.
  const u64 gb_off = (u64)((wave * 64 + lk) * 128 + lrc * 16);

  for (int t = 0; t < 1024; ++t) {
    // Prefetch wx_t (plain cached; consumed in tail, hidden under poll+gather).
    float4 wv = {0.f, 0.f, 0.f, 0.f};
    if (owner) wv = *(const float4*)(wxp + (size_t)(t * 8 + lr) * 2048 + e0 + lk * 4);

    // Poll: wave 0 only; lane watches flags[2*lane], flags[2*lane+1].
    if (t > 0 && wave == 0) {
      const u64* fp = (const u64*)flags + lane;
      for (;;) {
        const u64 fv = __hip_atomic_load(fp, __ATOMIC_RELAXED, __HIP_MEMORY_SCOPE_AGENT);
        if (__all(((int)fv >= t) && ((int)(fv >> 32) >= t))) break;
        __builtin_amdgcn_s_sleep(1);
      }
    }
    __syncthreads();   // A

    // ---- register-direct gather: hi then lo, all 32 loads in flight ----
    const u64 pb = hbase + (u64)(t & 1) * 65536 + gb_off;
    u32x4 sh[16], sl[16];
#pragma unroll
    for (int ks = 0; ks < 16; ++ks) sh[ks] = llc_load16(pb + (u64)ks * 512);
#pragma unroll
    for (int ks = 0; ks < 16; ++ks) sl[ks] = llc_load16(pb + 32768 + (u64)ks * 512);
    asm volatile("s_waitcnt vmcnt(16)" ::: "memory");   // hi complete
    __builtin_amdgcn_sched_barrier(0);

    // ---- hi MFMAs: ph += Ah.Bh ; pl += Al.Bh (lo loads still in flight) ----
    floatx4 ph[4] = {};
    floatx4 pl[4] = {};
#pragma unroll
    for (int ks = 0; ks < 16; ++ks) {
      const half8 bh = __builtin_bit_cast(half8, sh[ks]);
      ph[ks & 3] = __builtin_amdgcn_mfma_f32_16x16x32_f16(afh[ks], bh, ph[ks & 3], 0, 0, 0);
      pl[ks & 3] = __builtin_amdgcn_mfma_f32_16x16x32_f16(afl[ks], bh, pl[ks & 3], 0, 0, 0);
    }
    asm volatile("s_waitcnt vmcnt(0)" ::: "memory");    // lo complete
    __builtin_amdgcn_sched_barrier(0);

    // ---- lo MFMAs: pl += Ah.Bl ----
#pragma unroll
    for (int ks = 0; ks < 16; ++ks) {
      const half8 bl = __builtin_bit_cast(half8, sl[ks]);
      pl[ks & 3] = __builtin_amdgcn_mfma_f32_16x16x32_f16(afh[ks], bl, pl[ks & 3], 0, 0, 0);
    }
    const floatx4 pt = (ph[0] + ph[1] + ph[2] + ph[3]) +
                       (pl[0] + pl[1] + pl[2] + pl[3]) * SPLIT_R;
    *(floatx4*)&red[(wave * 64 + lane) * 4] = pt;
    __syncthreads();   // C

    if (tid < 64) {
      const floatx4* R = (const floatx4*)red;
      const floatx4 s = R[lane] + R[64 + lane] + R[128 + lane] + R[192 + lane];
      union { _Float16 h[4]; u64 u; } hv, lv, ov;
      if (owner) {
        hr0 += alpha * fast_tanh(s[0] + wv.x);
        hr1 += alpha * fast_tanh(s[1] + wv.y);
        hr2 += alpha * fast_tanh(s[2] + wv.z);
        hr3 += alpha * fast_tanh(s[3] + wv.w);
        hv.h[0] = (_Float16)hr0; hv.h[1] = (_Float16)hr1;
        hv.h[2] = (_Float16)hr2; hv.h[3] = (_Float16)hr3;
        lv.h[0] = (_Float16)((hr0 - (float)hv.h[0]) * SPLIT_S);
        lv.h[1] = (_Float16)((hr1 - (float)hv.h[1]) * SPLIT_S);
        lv.h[2] = (_Float16)((hr2 - (float)hv.h[2]) * SPLIT_S);
        lv.h[3] = (_Float16)((hr3 - (float)hv.h[3]) * SPLIT_S);
        // MALL-atomic publish: chunk 2g+(lk>>1), row lr, byte-half (lk&1).
        const u64 dst = hbase + (u64)((t + 1) & 1) * 65536 +
                        (u64)((2 * g + (lk >> 1)) * 128 + lr * 16 + (lk & 1) * 8);
        mall_swap8(dst,         hv.u);   // hi
        mall_swap8(dst + 32768, lv.u);   // lo
      }
      // Ack at MALL (atomics complete at the coherence point), then flag.
      asm volatile("s_waitcnt vmcnt(0)" ::: "memory");
      if (lane == 0) mall_swap4(flag_base + (u64)g * 4, t + 1);
      if (owner) {
        // outs consumed only by the next dispatch -> off the critical path.
        ov.h[0] = (_Float16)((hr0 * hr0 / (1.f + __expf(-hr0))) * 0.125f);
        ov.h[1] = (_Float16)((hr1 * hr1 / (1.f + __expf(-hr1))) * 0.125f);
        ov.h[2] = (_Float16)((hr2 * hr2 / (1.f + __expf(-hr2))) * 0.125f);
        ov.h[3] = (_Float16)((hr3 * hr3 / (1.f + __expf(-hr3))) * 0.125f);
        *(u64*)(outs + (size_t)(lr * 1024 + t) * 2048 + e0 + lk * 4) = ov.u;
      }
    }
    // red overwrite for t+1 is safe: waves block at barrier A until wave0
    // (which finished its red reads) arrives there after the tail.
  }
}

// ---------------------------------------------------------------------------
extern "C" void kernel_launch(void* const* d_in, const int* in_sizes, int n_in,
                              void* d_out, int out_size, void* d_ws, size_t ws_size,
                              hipStream_t stream)
{
  (void)in_sizes; (void)n_in; (void)out_size; (void)ws_size;
  const float* x    = (const float*)d_in[0];
  const float* h0   = (const float*)d_in[1];
  const float* Win  = (const float*)d_in[2];
  const float* Wx   = (const float*)d_in[3];
  const float* Wh   = (const float*)d_in[4];
  const float* bias = (const float*)d_in[5];
  const float* lal  = (const float*)d_in[6];
  const float* Wout = (const float*)d_in[7];

  char* ws = (char*)d_ws;
  _Float16* Uhi   = (_Float16*)(ws);                 // 33,554,432 B
  _Float16* Ulo   = (_Float16*)(ws + 33554432);      // 33,554,432 B
  _Float16* OUTS  = (_Float16*)(ws);                 // aliases Uhi
  _Float16* WoutF = (_Float16*)(ws + 33554432);      // aliases Ulo
  _Float16* Whi   = (_Float16*)(ws + 67108864);      //  8,388,608 B
  _Float16* Wlo   = (_Float16*)(ws + 75497472);      //  8,388,608 B
  char*     hpub  = ws + 83886080;                   //    131,072 B
  int*      flags = (int*)(ws + 84017152);           //        512 B
  _Float16* xhi   = (_Float16*)d_out;                // 33,554,432 B
  _Float16* xlo   = (_Float16*)((char*)d_out + 33554432);
  float*    wxbuf = (float*)d_out;

  const dim3 gg(16, 64);  // N/128, M/128

  k_split_xw<<<2048, 256, 0, stream>>>(x, Win, xhi, xlo, Whi, Wlo);
  k_gemm_ps<0><<<gg, 256, 0, stream>>>(xhi, xlo, Whi, Wlo, Uhi, Ulo,
                                       nullptr, nullptr, 8192, 2048, 2048);
  k_convertB<<<512, 256, 0, stream>>>(Wx, h0, Whi, Wlo, hpub, flags);
  k_gemm_ps<1><<<gg, 256, 0, stream>>>(Uhi, Ulo, Whi, Wlo, nullptr, nullptr,
                                       wxbuf, bias, 8192, 2048, 2048);
  k_convert2<<<512, 256, 0, stream>>>(Wout, WoutF);
  k_recur<<<128, 256, 0, stream>>>(Wh, wxbuf, h0, lal, OUTS, hpub, flags);
  k_gemm_out<<<gg, 256, 0, stream>>>(OUTS, WoutF, (float*)d_out, 8192, 2048, 2048);
}